// Round 1
// 293.327 us; speedup vs baseline: 1.0469x; 1.0469x over previous
//
#include <hip/hip_runtime.h>
#include <math.h>

#define NUM_NODES 94
#define SEQ_LEN 784
#define OUT_CLASSES 10
#define EPB 16              // batch elements per block (MFMA N dim)
#define NW 6                // waves per block: 6 x 16 rows = 96 >= 94
#define YP 104              // y LDS row stride in f16 (bank-balanced, 8B/16B aligned)
#define SP 796              // input LDS row stride in f32 (2-way max on broadcast read)

#define TWO_GAMMA 0.2f
#define OM2 0.0503551324598949f            // (2*pi/28)^2
#define INV_SQRT_N 0.103142124625879       // 1/sqrt(94)
#define LOG2E 1.4426950408889634
// exp2 arg = 2A*log2e -> fold 2*INV_SQRT_N*LOG2E into all I-path weights
#define WSCALE ((float)(2.0 * INV_SQRT_N * LOG2E))

typedef _Float16 half8 __attribute__((ext_vector_type(8)));
typedef _Float16 half4 __attribute__((ext_vector_type(4)));
typedef float    floatx4 __attribute__((ext_vector_type(4)));
typedef float    f2 __attribute__((ext_vector_type(2)));

// MFMA rewrite: 16 batch elements per block share one recurrent update.
// Wave m owns output rows 16m..16m+15 for all 16 elements:
//   D[r][e] = sum_k W[r][k] * y[e][k]  via 3x v_mfma_f32_16x16x32_f16 (K=96 padded).
// y exchanged cross-wave through double-buffered LDS ([e][YP] f16, row-contiguous
// so B-fragments are single b128 reads and publishes are single b64 writes).
// Dynamics per lane: 4 nodes (rows 16m+4h+0..3) for element e, packed f32x2.
__global__
__attribute__((amdgpu_flat_work_group_size(NW*64, NW*64)))
void horn_kernel(
    const float* __restrict__ input,   // (1024, 784)
    const float* __restrict__ w_ih,    // (94, 1)
    const float* __restrict__ b_ih,    // (94)
    const float* __restrict__ w_hh,    // (94, 94)
    const float* __restrict__ b_hh,    // (94)
    const float* __restrict__ w_ro,    // (10, 94)
    const float* __restrict__ b_ro,    // (10)
    float* __restrict__ out)           // (1024, 10)
{
    __shared__ __align__(16) float    sinl[EPB * SP];        // 50,944 B (reused as xsh)
    __shared__ __align__(16) _Float16 ybuf[2][EPB * YP];     //  6,656 B

    const int tid  = threadIdx.x;
    const int m    = tid >> 6;         // wave id 0..5: rows 16m..16m+15
    const int lane = tid & 63;
    const int e    = lane & 15;        // element (B/D column); also A row-within-tile
    const int h    = lane >> 4;        // 0..3 (k-group / D row-group)
    const int bb   = blockIdx.x;       // 64 blocks, 16 elements each

    // ---- preload 16 input rows to LDS (f32, float4-coalesced) ----
    {
        const floatx4* in4 = (const floatx4*)(input + (size_t)bb * EPB * SEQ_LEN);
        for (int idx = tid; idx < EPB * (SEQ_LEN / 4); idx += NW * 64) {
            int ee = idx / (SEQ_LEN / 4);
            int cc = idx - ee * (SEQ_LEN / 4);
            *(floatx4*)&sinl[ee * SP + 4 * cc] = in4[idx];
        }
    }
    // ---- zero both y buffers (y0 = 0) ----
    {
        float* yz = (float*)&ybuf[0][0];
        for (int i = tid; i < (2 * EPB * YP) / 2; i += NW * 64) yz[i] = 0.0f;
    }

    // ---- A fragments (constant over time): lane holds W[16m+e][32j+8h+i]*WSCALE ----
    const int arow = 16 * m + e;
    half8 a0, a1, a2;
    #pragma unroll
    for (int i = 0; i < 8; i++) {
        const int kb = 8 * h + i;
        a0[i] = (_Float16)((arow < NUM_NODES && kb      < NUM_NODES) ? w_hh[arow * NUM_NODES + kb     ] * WSCALE : 0.0f);
        a1[i] = (_Float16)((arow < NUM_NODES && kb + 32 < NUM_NODES) ? w_hh[arow * NUM_NODES + kb + 32] * WSCALE : 0.0f);
        a2[i] = (_Float16)((arow < NUM_NODES && kb + 64 < NUM_NODES) ? w_hh[arow * NUM_NODES + kb + 64] * WSCALE : 0.0f);
    }

    // ---- per-lane node constants: rows r0..r0+3 (D rows 4h+i of tile m) ----
    const int r0 = 16 * m + 4 * h;
    f2 wih01, wih23, bias01, bias23;
    {
        float w[4], b[4];
        #pragma unroll
        for (int i = 0; i < 4; i++) {
            const int r = r0 + i;
            w[i] = (r < NUM_NODES) ? w_ih[r] * WSCALE : 0.0f;
            b[i] = (r < NUM_NODES) ? (b_ih[r] + b_hh[r]) * WSCALE : 0.0f;
        }
        wih01[0] = w[0]; wih01[1] = w[1]; wih23[0] = w[2]; wih23[1] = w[3];
        bias01[0] = b[0]; bias01[1] = b[1]; bias23[0] = b[2]; bias23[1] = b[3];
    }

    f2 x01 = {0.0f, 0.0f}, x23 = {0.0f, 0.0f};
    f2 y01 = {0.0f, 0.0f}, y23 = {0.0f, 0.0f};

    const int rdoff = e * YP + 8 * h;   // B-frag base (16B aligned)
    const int wroff = e * YP + r0;      // y publish base (8B aligned)
    const int sbase = e * SP;

    const floatx4 zf4 = {0.0f, 0.0f, 0.0f, 0.0f};
    const f2 ng = {-TWO_GAMMA, -TWO_GAMMA};
    const f2 no = {-OM2, -OM2};

    __syncthreads();   // LDS init visible to all waves

    #define HSTEP(RD, WR, T) do {                                                  \
        half8 b0 = *(const half8*)&(RD)[rdoff];                                    \
        half8 b1 = *(const half8*)&(RD)[rdoff + 32];                               \
        half8 b2 = *(const half8*)&(RD)[rdoff + 64];                               \
        float st = sinl[sbase + (T)];                                              \
        floatx4 d0 = __builtin_amdgcn_mfma_f32_16x16x32_f16(a0, b0, zf4, 0, 0, 0); \
        floatx4 d1 = __builtin_amdgcn_mfma_f32_16x16x32_f16(a1, b1, zf4, 0, 0, 0); \
        floatx4 d2 = __builtin_amdgcn_mfma_f32_16x16x32_f16(a2, b2, zf4, 0, 0, 0); \
        f2 S01 = { d0[0] + d1[0] + d2[0], d0[1] + d1[1] + d2[1] };                 \
        f2 S23 = { d0[2] + d1[2] + d2[2], d0[3] + d1[3] + d2[3] };                 \
        f2 st2 = { st, st };                                                       \
        f2 e01 = st2 * wih01 + (bias01 + S01);                                     \
        f2 e23 = st2 * wih23 + (bias23 + S23);                                     \
        f2 t01, t23;                                                               \
        t01[0] = 0.5f - __builtin_amdgcn_rcpf(__builtin_amdgcn_exp2f(e01[0]) + 1.0f); \
        t01[1] = 0.5f - __builtin_amdgcn_rcpf(__builtin_amdgcn_exp2f(e01[1]) + 1.0f); \
        t23[0] = 0.5f - __builtin_amdgcn_rcpf(__builtin_amdgcn_exp2f(e23[0]) + 1.0f); \
        t23[1] = 0.5f - __builtin_amdgcn_rcpf(__builtin_amdgcn_exp2f(e23[1]) + 1.0f); \
        t01 = ng * y01 + t01;  t01 = no * x01 + t01;                               \
        t23 = ng * y23 + t23;  t23 = no * x23 + t23;                               \
        x01 += y01;  x23 += y23;                                                   \
        y01 += t01;  y23 += t23;                                                   \
        half4 yh;                                                                  \
        yh[0] = (_Float16)y01[0]; yh[1] = (_Float16)y01[1];                        \
        yh[2] = (_Float16)y23[0]; yh[3] = (_Float16)y23[1];                        \
        *(half4*)&(WR)[wroff] = yh;                                                \
        __syncthreads();                                                           \
    } while (0)

    for (int t = 0; t < SEQ_LEN; t += 2) {
        HSTEP(ybuf[0], ybuf[1], t);
        HSTEP(ybuf[1], ybuf[0], t + 1);
    }
    #undef HSTEP

    // ---- epilogue: gather x (f32, reuse sin LDS), project to classes ----
    float* xsh = sinl;
    {
        floatx4 xv = { x01[0], x01[1], x23[0], x23[1] };
        *(floatx4*)&xsh[e * YP + r0] = xv;
    }
    __syncthreads();

    if (tid < EPB * OUT_CLASSES) {
        const int ee = tid / OUT_CLASSES;
        const int c  = tid - ee * OUT_CLASSES;
        float acc = b_ro[c];
        #pragma unroll 2
        for (int r = 0; r < NUM_NODES; r++)
            acc += xsh[ee * YP + r] * w_ro[c * NUM_NODES + r];
        out[((size_t)bb * EPB + ee) * OUT_CLASSES + c] = acc;
    }
}

extern "C" void kernel_launch(void* const* d_in, const int* in_sizes, int n_in,
                              void* d_out, int out_size, void* d_ws, size_t ws_size,
                              hipStream_t stream) {
    const float* input = (const float*)d_in[0];
    const float* w_ih  = (const float*)d_in[1];
    const float* b_ih  = (const float*)d_in[2];
    const float* w_hh  = (const float*)d_in[3];
    const float* b_hh  = (const float*)d_in[4];
    const float* w_ro  = (const float*)d_in[5];
    const float* b_ro  = (const float*)d_in[6];
    float* out = (float*)d_out;

    const int batch = in_sizes[0] / SEQ_LEN;   // 1024
    dim3 grid(batch / EPB);                    // 64 blocks of 16 elements
    dim3 block(NW * 64);                       // 6 waves

    hipLaunchKernelGGL(horn_kernel, grid, block, 0, stream,
                       input, w_ih, b_ih, w_hh, b_hh, w_ro, b_ro, out);
}